// Round 3
// baseline (296.873 us; speedup 1.0000x reference)
//
#include <hip/hip_runtime.h>

// Problem: B=65536, T=20, M=4, D=4, L=3, H=2, FF=16, S=5; N=B*T=1,310,720
// independent sequences; one thread per sequence, fully unrolled in registers.
//
// Dtype resolution (R0-R2 evidence): all inputs fp32, OUTPUT fp32 (harness
// reads d_out as float32 since the JAX reference returns fp32; R2's bf16
// writes produced structural garbage = 5.53 absmax). Input-side runtime
// sniff retained as cheap insurance (one 1-block kernel).

enum {
  OFF_CLS  = 0,    // 4
  OFF_WQKV = 4,    // 144
  OFF_BQKV = 148,  // 36
  OFF_WO   = 184,  // 48
  OFF_BO   = 232,  // 12
  OFF_W1   = 244,  // 192
  OFF_B1   = 436,  // 48
  OFF_W2   = 484,  // 192
  OFF_B2   = 676,  // 12
  WF_TOTAL = 688,
  FLAG_XF32 = 688  // wf[688] as int: 1 if regional_states is fp32
};

__device__ __forceinline__ float bf2f(unsigned short u) {
  unsigned int x = ((unsigned int)u) << 16;
  float f;
  __builtin_memcpy(&f, &x, 4);
  return f;
}

// bf16-packed vs fp32 discrimination on 16 words: bf16 data's low halves are
// moderate-exponent bf16s or zero; fp32 data's low halves are random mantissa
// bits (each passes ~20% -> P(>=15 of 16) ~ 1e-10).
__device__ __forceinline__ bool is_bf16_packed(const unsigned int* w) {
  int pass = 0;
#pragma unroll
  for (int i = 0; i < 16; ++i) {
    unsigned int lo = w[i] & 0xFFFFu;
    unsigned int e = (lo >> 7) & 0xFFu;
    if (lo == 0u || (e >= 90u && e <= 140u)) ++pass;
  }
  return pass >= 15;
}

// ---- prep: sniff dtypes, materialize fp32 weights in d_ws, publish flag.
// Must run every call: d_ws is re-poisoned before each timed launch. ----
__global__ void mpt_prep(const void* __restrict__ cls,
                         const void* __restrict__ Wqkv,
                         const void* __restrict__ bqkv,
                         const void* __restrict__ Wo,
                         const void* __restrict__ bo,
                         const void* __restrict__ W1,
                         const void* __restrict__ b1,
                         const void* __restrict__ W2,
                         const void* __restrict__ b2,
                         const void* __restrict__ xin,
                         float* __restrict__ wf) {
  const bool wbf = is_bf16_packed((const unsigned int*)Wqkv);
  const bool xbf = is_bf16_packed((const unsigned int*)xin);
  if (threadIdx.x == 0) ((int*)wf)[FLAG_XF32] = xbf ? 0 : 1;
  for (int i = threadIdx.x; i < WF_TOTAL; i += 256) {
    const void* src;
    int k;
    if      (i < OFF_WQKV) { src = cls;  k = i - OFF_CLS;  }
    else if (i < OFF_BQKV) { src = Wqkv; k = i - OFF_WQKV; }
    else if (i < OFF_WO)   { src = bqkv; k = i - OFF_BQKV; }
    else if (i < OFF_BO)   { src = Wo;   k = i - OFF_WO;   }
    else if (i < OFF_W1)   { src = bo;   k = i - OFF_BO;   }
    else if (i < OFF_B1)   { src = W1;   k = i - OFF_W1;   }
    else if (i < OFF_W2)   { src = b1;   k = i - OFF_B1;   }
    else if (i < OFF_B2)   { src = W2;   k = i - OFF_W2;   }
    else                   { src = b2;   k = i - OFF_B2;   }
    wf[i] = wbf ? bf2f(((const unsigned short*)src)[k])
                : ((const float*)src)[k];
  }
}

// ---- main: one thread per sequence; weights via uniform address -> scalar
// loads/L1; x state (5x4 fp32) in registers. ----
__global__ __launch_bounds__(256) void mpt_main(
    const void* __restrict__ xin,     // (N,16) fp32 (or bf16; flag decides)
    const float* __restrict__ wf,     // fp32 weights + flag in d_ws
    float* __restrict__ out,          // [N*4 F_g | N*16 subregion] fp32
    int N) {
  const int n = blockIdx.x * 256 + threadIdx.x;
  if (n >= N) return;

  const int xf32 = ((const int*)wf)[FLAG_XF32];  // wave-uniform

  // positional encoding, S=5 x D=4 (cols: sin p, cos p, sin .01p, cos .01p)
  const float pe[5][4] = {
    { 0.0f,                1.0f,                0.0f,                1.0f               },
    { 0.8414709848078965f, 0.5403023058681398f, 0.0099998333341667f, 0.9999500004166653f },
    { 0.9092974268256817f,-0.4161468365471424f, 0.0199986666933331f, 0.9998000066665778f },
    { 0.1411200080598672f,-0.9899924966004454f, 0.0299955002024957f, 0.9995500337489875f },
    {-0.7568024953079283f,-0.6536436208636119f, 0.0399893341866342f, 0.9992001066609779f }
  };

  float raw[16];
  if (xf32) {
    const float4* pf = reinterpret_cast<const float4*>((const float*)xin + (size_t)n * 16);
#pragma unroll
    for (int r = 0; r < 4; ++r) {
      float4 t = pf[r];
      raw[r * 4 + 0] = t.x; raw[r * 4 + 1] = t.y;
      raw[r * 4 + 2] = t.z; raw[r * 4 + 3] = t.w;
    }
  } else {
    struct alignas(16) U8 { unsigned short v[8]; };
    const U8* p = reinterpret_cast<const U8*>((const unsigned short*)xin + (size_t)n * 16);
    U8 a0 = p[0], a1 = p[1];
#pragma unroll
    for (int j = 0; j < 8; ++j) {
      raw[j]     = bf2f(a0.v[j]);
      raw[8 + j] = bf2f(a1.v[j]);
    }
  }

  float x[5][4];
#pragma unroll
  for (int d = 0; d < 4; ++d) x[0][d] = wf[OFF_CLS + d] + pe[0][d];
#pragma unroll
  for (int r = 0; r < 4; ++r)
#pragma unroll
    for (int d = 0; d < 4; ++d) x[1 + r][d] = raw[r * 4 + d] + pe[1 + r][d];

  const float scale = 0.70710678118654752f;  // 1/sqrt(head_dim=2)

#pragma unroll
  for (int l = 0; l < 3; ++l) {
    const float* Wqkv = wf + OFF_WQKV + l * 48;
    const float* bqkv = wf + OFF_BQKV + l * 12;
    const float* Wo   = wf + OFF_WO   + l * 16;
    const float* bo   = wf + OFF_BO   + l * 4;
    const float* W1   = wf + OFF_W1   + l * 64;
    const float* b1   = wf + OFF_B1   + l * 16;
    const float* W2   = wf + OFF_W2   + l * 64;
    const float* b2   = wf + OFF_B2   + l * 4;

    // qkv = x @ Wqkv^T + bqkv ; rows 0..3=q, 4..7=k, 8..11=v
    float q[5][4], k[5][4], v[5][4];
#pragma unroll
    for (int s = 0; s < 5; ++s) {
#pragma unroll
      for (int j = 0; j < 12; ++j) {
        float a = bqkv[j];
#pragma unroll
        for (int d = 0; d < 4; ++d) a = fmaf(x[s][d], Wqkv[j * 4 + d], a);
        if (j < 4)      q[s][j] = a;
        else if (j < 8) k[s][j - 4] = a;
        else            v[s][j - 8] = a;
      }
    }

    // attention: head h uses dims {2h, 2h+1}
    float o[5][4];
#pragma unroll
    for (int h = 0; h < 2; ++h) {
      const int d0 = 2 * h, d1 = 2 * h + 1;
#pragma unroll
      for (int si = 0; si < 5; ++si) {
        float sc[5];
        float mx = -3.0e38f;
#pragma unroll
        for (int sj = 0; sj < 5; ++sj) {
          float s0 = q[si][d0] * k[sj][d0] + q[si][d1] * k[sj][d1];
          sc[sj] = s0 * scale;
          mx = fmaxf(mx, sc[sj]);
        }
        float den = 0.f, o0 = 0.f, o1 = 0.f;
#pragma unroll
        for (int sj = 0; sj < 5; ++sj) {
          float e = __expf(sc[sj] - mx);
          den += e;
          o0 = fmaf(e, v[sj][d0], o0);
          o1 = fmaf(e, v[sj][d1], o1);
        }
        float inv = __builtin_amdgcn_rcpf(den);
        o[si][d0] = o0 * inv;
        o[si][d1] = o1 * inv;
      }
    }

    // out-proj + residual, then FFN + residual
#pragma unroll
    for (int s = 0; s < 5; ++s) {
      float nx[4];
#pragma unroll
      for (int i = 0; i < 4; ++i) {
        float a = bo[i];
#pragma unroll
        for (int j = 0; j < 4; ++j) a = fmaf(o[s][j], Wo[i * 4 + j], a);
        nx[i] = x[s][i] + a;
      }
#pragma unroll
      for (int i = 0; i < 4; ++i) x[s][i] = nx[i];

      float acc[4] = {b2[0], b2[1], b2[2], b2[3]};
#pragma unroll
      for (int f = 0; f < 16; ++f) {
        float hs = b1[f];
#pragma unroll
        for (int d = 0; d < 4; ++d) hs = fmaf(x[s][d], W1[f * 4 + d], hs);
        hs = fmaxf(hs, 0.f);
#pragma unroll
        for (int i = 0; i < 4; ++i) acc[i] = fmaf(hs, W2[i * 16 + f], acc[i]);
      }
#pragma unroll
      for (int i = 0; i < 4; ++i) x[s][i] += acc[i];
    }
  }

  // outputs (fp32): F_g = x[0] -> out[n*4 + i];
  // subregion = x[1..4] -> out[N*4 + n*16 + ...]
  float4 fg = make_float4(x[0][0], x[0][1], x[0][2], x[0][3]);
  *reinterpret_cast<float4*>(out + (size_t)n * 4) = fg;

  float* sub = out + (size_t)N * 4 + (size_t)n * 16;
#pragma unroll
  for (int r = 0; r < 4; ++r) {
    float4 t = make_float4(x[1 + r][0], x[1 + r][1], x[1 + r][2], x[1 + r][3]);
    *reinterpret_cast<float4*>(sub + r * 4) = t;
  }
}

extern "C" void kernel_launch(void* const* d_in, const int* in_sizes, int n_in,
                              void* d_out, int out_size, void* d_ws, size_t ws_size,
                              hipStream_t stream) {
  float* wf = (float*)d_ws;

  mpt_prep<<<1, 256, 0, stream>>>(
      d_in[1],  // cls_token
      d_in[2],  // Wqkv
      d_in[3],  // bqkv
      d_in[4],  // Wo
      d_in[5],  // bo
      d_in[6],  // W1
      d_in[7],  // b1
      d_in[8],  // W2
      d_in[9],  // b2
      d_in[0],  // regional_states (dtype sniff)
      wf);

  const int N = in_sizes[0] / 16;  // B*T sequences
  mpt_main<<<(N + 255) / 256, 256, 0, stream>>>(
      d_in[0], wf, (float*)d_out, N);
}